// Round 15
// baseline (510.188 us; speedup 1.0000x reference)
//
#include <hip/hip_runtime.h>
#include <math.h>

#define N_NODES 524288
#define E 64
#define NC 8
#define TILE 128
#define BPS3 512                 // kA blocks per side
#define ITERS3 8                 // 512 blocks * 8 tiles * 128 nodes = 524288

// ---- workspace layout (float offsets) ----
#define OFF_WQ_V    0      // WQ[hc][j]  hc=h*8+c  (2048)
#define OFF_SB_V    2048   // sbias[hc]            (32)
#define OFF_WQ_C    2080
#define OFF_SB_C    4128
#define OFF_ACC_V   4160   // 2600 floats (totals, written by kR)
#define OFF_ACC_C   6760
#define OFF_FUSED_V 9360   // 512
#define OFF_FUSED_C 9872
// gacc internal layout:
#define ACC_SXW 0      // [(h*64+j)*8 + c]  (2048)  sum of p_h * xs_j per class
#define ACC_AXS 2048   // [j*8 + c]         (512)   sum of xs_j per class
#define ACC_P   2560   // [h*8 + c]         (32)    sum of p_h per class
#define ACC_CNT 2592   // [c]               (8)
#define ACC_TOTAL 2600

#define XSTR 136       // halfword stride for XT / P rows (272B, 16B-aligned)

typedef __attribute__((ext_vector_type(8))) short bf16x8;
typedef __attribute__((ext_vector_type(4))) float f32x4;

__device__ __forceinline__ unsigned short f2bf(float f) {
    union { float f; unsigned u; } v; v.f = f;
    return (unsigned short)((v.u + 0x7fffu + ((v.u >> 16) & 1u)) >> 16);  // RNE
}
__device__ __forceinline__ float bf2f(unsigned short s) {
    union { unsigned u; float f; } v; v.u = ((unsigned)s) << 16;
    return v.f;
}
__device__ __forceinline__ bf16x8 pack8s(float4 a, float4 b) {
    bf16x8 r;
    r[0] = (short)f2bf(a.x); r[1] = (short)f2bf(a.y);
    r[2] = (short)f2bf(a.z); r[3] = (short)f2bf(a.w);
    r[4] = (short)f2bf(b.x); r[5] = (short)f2bf(b.y);
    r[6] = (short)f2bf(b.z); r[7] = (short)f2bf(b.w);
    return r;
}
__device__ __forceinline__ bf16x8 load8bf(const float* p) {
    return pack8s(*(const float4*)p, *(const float4*)(p + 4));
}

// map flat partial index i (= hc*65+j, hc<40) to gacc offset
__device__ __forceinline__ int acc_dst(int i) {
    const int hc = i / 65, j = i - hc*65;
    if (hc < 32) return (j < 64) ? (ACC_SXW + ((hc>>3)*64 + j)*8 + (hc&7)) : (ACC_P + hc);
    const int c2 = hc - 32;
    return (j < 64) ? (ACC_AXS + j*8 + c2) : (ACC_CNT + c2);
}

// ---------------- kernel Q: fold Wq,Wk,Ws into WQ/sbias ----------------
__global__ __launch_bounds__(512) void kQ(
    const float* __restrict__ sem_v, const float* __restrict__ sem_c,
    const float* __restrict__ Wqkv_v, const float* __restrict__ bqkv_v,
    const float* __restrict__ Wqkv_c, const float* __restrict__ bqkv_c,
    const float* __restrict__ Ws_v, const float* __restrict__ bs_v,
    const float* __restrict__ Ws_c, const float* __restrict__ bs_c,
    float* __restrict__ ws)
{
    const int side = blockIdx.x;
    const float* sem  = side ? sem_c  : sem_v;
    const float* Wqkv = side ? Wqkv_c : Wqkv_v;
    const float* bqkv = side ? bqkv_c : bqkv_v;
    const float* Ws   = side ? Ws_c   : Ws_v;
    const float* bs   = side ? bs_c   : bs_v;
    float* WQo  = ws + (side ? OFF_WQ_C : OFF_WQ_V);
    float* sbo  = ws + (side ? OFF_SB_C : OFF_SB_V);
    const int tid = threadIdx.x;

    __shared__ float s_q[NC][E];
    __shared__ float s_qk[32][E];   // [hc][e]
    {   // q[c][e] = (bq[e] + sem[c]·Wq[e]) * (1/sqrt(16))
        const int c = tid >> 6, e = tid & 63;
        float a = bqkv[e];
        for (int j = 0; j < E; ++j) a += sem[c*E + j] * Wqkv[e*E + j];
        s_q[c][e] = a * 0.25f;
    }
    __syncthreads();

    const float* Wk = Wqkv + E*E;
    const float* bk = bqkv + E;
    for (int r = 0; r < 4; ++r) {
        int idx = r*512 + tid;             // idx = hc*64 + e
        int hc = idx >> 6, e = idx & 63;
        int h = hc >> 3, c = hc & 7;
        float a = 0.0f;
        for (int d = 0; d < 16; ++d) a += Wk[(h*16+d)*E + e] * s_q[c][h*16+d];
        s_qk[hc][e] = a;
    }
    __syncthreads();

    // WQ[hc][j] = sum_e qk[hc][e] * Ws[e][j]
    for (int r = 0; r < 4; ++r) {
        int idx = r*512 + tid;
        int hc = idx >> 6, j = idx & 63;
        float a = 0.0f;
        for (int e = 0; e < 64; ++e) a += s_qk[hc][e] * Ws[e*64 + j];
        WQo[idx] = a;
    }
    // sbias[hc] = qb[hc] + sum_e qk[hc][e]*bs[e]
    if (tid < 32) {
        int hc = tid, h = hc >> 3, c = hc & 7;
        float a = 0.0f;
        for (int d = 0; d < 16; ++d) a += bk[h*16+d] * s_q[c][h*16+d];
        for (int e = 0; e < 64; ++e) a += s_qk[hc][e] * bs[e];
        sbo[tid] = a;
    }
}

// ---------------- kernel A: double-MFMA segment attention, barrier-free hot loop ----------------
// R14 body with ONE change: __launch_bounds__(256, 3). Measured occupancy
// tracks the bounds 2nd arg exactly (R8:4->40%, R10:3->31%, R9/R14:2->21%),
// independent of LDS headroom and grid size -- the attribute pins residency.
// 3 x 47616 B = 139.5 KB <= 160 KB LDS; VGPR cap at bounds=3 is ~170 > the
// 128 this body compiles to under bounds=2, so no spill (R8's failure mode).
// Flush stays plain stores to disjoint d_out slots (no atomics; R13's win).
__global__ __launch_bounds__(256, 3) void kA(
    const float* __restrict__ xv, const float* __restrict__ xc,
    const int* __restrict__ clsv, const int* __restrict__ clsc,
    const float* __restrict__ Ws_v, const float* __restrict__ bs_v,
    const float* __restrict__ Ws_c, const float* __restrict__ bs_c,
    float* __restrict__ ws, float* __restrict__ outp)
{
    const int bid  = blockIdx.x;
    const int side = bid >> 9;
    const float* x    = side ? xc   : xv;
    const int*   cls  = side ? clsc : clsv;
    const float* Ws   = side ? Ws_c : Ws_v;
    const float* bs   = side ? bs_c : bs_v;
    const float* WQ   = ws + (side ? OFF_WQ_C : OFF_WQ_V);
    const float* sbia = ws + (side ? OFF_SB_C : OFF_SB_V);
    const int tid  = threadIdx.x;
    const int w    = tid >> 6;
    const int lane = tid & 63;
    const int li   = lane & 15, lg = lane >> 4;

    // LDS: XT 64x136 bf16 (17408 B) | P 48x136 bf16 (13056 B) | SC 128x33 f32 (16896 B) = 47360 B
    // ACCR (48x84 f32 = 16128 B) aliases XT; only touched after the post-loop __syncthreads().
    __shared__ __align__(16) unsigned char smem[47360];
    unsigned short* XT = (unsigned short*)(smem);
    unsigned short* P  = (unsigned short*)(smem + 17408);
    float*          SC = (float*)(smem + 30464);
    float*        ACCR = (float*)(smem);

    // ---- A-fragments: rows 0..63 = Ws (e), rows 64..95 = WQ (hc). Held in regs all kernel.
    bf16x8 AF[6][2];
    #pragma unroll
    for (int mb = 0; mb < 6; ++mb) {
        const int m = mb*16 + li;
        const float* src = (mb < 4) ? (Ws + m*64) : (WQ + (m - 64)*64);
        #pragma unroll
        for (int kb = 0; kb < 2; ++kb)
            AF[mb][kb] = load8bf(src + kb*32 + lg*8);
    }
    // per-thread bias registers (row-indexed: C/D row = lg*4+r)
    float bsr[16], sbr[8];
    #pragma unroll
    for (int mb = 0; mb < 4; ++mb)
        #pragma unroll
        for (int r = 0; r < 4; ++r) bsr[mb*4+r] = bs[mb*16 + lg*4 + r];
    #pragma unroll
    for (int sb = 0; sb < 2; ++sb)
        #pragma unroll
        for (int r = 0; r < 4; ++r) sbr[sb*4+r] = sbia[sb*16 + lg*4 + r];

    // constant "ones" B-block for MFMA2 (e-cols 64..79: col 64 = 1, rest 0)
    bf16x8 XB4;
    {
        const short v = (li == 0) ? (short)0x3F80 : (short)0;
        #pragma unroll
        for (int j = 0; j < 8; ++j) XB4[j] = v;
    }

    // P padding rows 40..47: zero once, read-only afterwards (barrier outside loop)
    for (int i = tid; i < 8*XSTR; i += 256) P[40*XSTR + i] = 0;
    __syncthreads();

    f32x4 acc2[3][5];
    #pragma unroll
    for (int a = 0; a < 3; ++a)
        #pragma unroll
        for (int b = 0; b < 5; ++b) acc2[a][b] = (f32x4){0.f,0.f,0.f,0.f};

    const int bloc = bid & (BPS3 - 1);

    // ---- depth-1 register prefetch of the x-tile + class (wave-own node) ----
    float4 pf[8];
    int pcls;
    {
        const int tb = (bloc * ITERS3) * TILE;
        #pragma unroll
        for (int nb = 0; nb < 2; ++nb) {
            const int nt = w*32 + nb*16 + li;
            const float* xp = x + (size_t)(tb + nt)*64 + lg*8;
            pf[nb*4+0] = *(const float4*)xp;
            pf[nb*4+1] = *(const float4*)(xp + 4);
            pf[nb*4+2] = *(const float4*)(xp + 32);
            pf[nb*4+3] = *(const float4*)(xp + 36);
        }
        pcls = cls[tb + w*32 + (lane & 31)];
    }

    for (int t = 0; t < ITERS3; ++t) {
        // consume prefetched tile into bf16 fragments
        bf16x8 B00 = pack8s(pf[0], pf[1]);
        bf16x8 B01 = pack8s(pf[2], pf[3]);
        bf16x8 B10 = pack8s(pf[4], pf[5]);
        bf16x8 B11 = pack8s(pf[6], pf[7]);
        const int myc = pcls;

        // issue next tile's loads now (consumed next iteration)
        if (t + 1 < ITERS3) {
            const int tb = (bloc * ITERS3 + t + 1) * TILE;
            #pragma unroll
            for (int nb = 0; nb < 2; ++nb) {
                const int nt = w*32 + nb*16 + li;
                const float* xp = x + (size_t)(tb + nt)*64 + lg*8;
                pf[nb*4+0] = *(const float4*)xp;
                pf[nb*4+1] = *(const float4*)(xp + 4);
                pf[nb*4+2] = *(const float4*)(xp + 32);
                pf[nb*4+3] = *(const float4*)(xp + 36);
            }
            pcls = cls[tb + w*32 + (lane & 31)];
        }

        // ---- MFMA1: [Ws;WQ] @ x^T -> xs^T (to XT, bf16) and scores (to SC, f32) ----
        #pragma unroll
        for (int nb = 0; nb < 2; ++nb) {
            const int nt = w*32 + nb*16 + li;
            const bf16x8 Bk0 = nb ? B10 : B00;
            const bf16x8 Bk1 = nb ? B11 : B01;
            f32x4 Cf[6];
            #pragma unroll
            for (int mb = 0; mb < 6; ++mb) {
                f32x4 c0 = {0.f, 0.f, 0.f, 0.f};
                c0 = __builtin_amdgcn_mfma_f32_16x16x32_bf16(AF[mb][0], Bk0, c0, 0, 0, 0);
                c0 = __builtin_amdgcn_mfma_f32_16x16x32_bf16(AF[mb][1], Bk1, c0, 0, 0, 0);
                Cf[mb] = c0;
            }
            // xs^T rows: e = mb*16 + lg*4 + r, col = nt
            #pragma unroll
            for (int mb = 0; mb < 4; ++mb)
                #pragma unroll
                for (int r = 0; r < 4; ++r)
                    XT[(mb*16 + lg*4 + r)*XSTR + nt] = f2bf(Cf[mb][r] + bsr[mb*4+r]);
            // scores: hc = sb*16 + lg*4 + r
            #pragma unroll
            for (int sb = 0; sb < 2; ++sb)
                #pragma unroll
                for (int r = 0; r < 4; ++r)
                    SC[nt*33 + sb*16 + lg*4 + r] = Cf[4+sb][r] + sbr[sb*4+r];
        }
        // zero this wave's P column strip (rows 0..39)
        {
            const uint4 z4 = {0u,0u,0u,0u};
            for (int i = lane; i < 160; i += 64) {
                const int row = i >> 2, cg = i & 3;
                *(uint4*)&P[row*XSTR + w*32 + cg*8] = z4;
            }
        }

        // ---- p = exp(score): lane handles node w*32+(lane&31), heads 2*(lane>>5)..+1 ----
        // (wave-private: reads SC / writes P only in this wave's column strip)
        {
            const int nt = w*32 + (lane & 31), hp = lane >> 5;
            const float sa  = SC[nt*33 + (hp*2    )*8 + myc];
            const float sb2 = SC[nt*33 + (hp*2 + 1)*8 + myc];
            // softmax-max skipped: |scores| << 1 at this weight scale (shift-invariant w)
            P[((hp*2    )*8 + myc)*XSTR + nt] = f2bf(__expf(sa));
            P[((hp*2 + 1)*8 + myc)*XSTR + nt] = f2bf(__expf(sb2));
            if (hp == 0) P[(32 + myc)*XSTR + nt] = 0x3F80;   // indicator row
        }

        // ---- MFMA2: ACC[48 hc][80 e] += P @ [xs | 1]; wave w covers its own 32-node k-range ----
        {
            const int kbase = w*32 + lg*8;
            bf16x8 PA0 = *(const bf16x8*)&P[(0*16 + li)*XSTR + kbase];
            bf16x8 PA1 = *(const bf16x8*)&P[(1*16 + li)*XSTR + kbase];
            bf16x8 PA2 = *(const bf16x8*)&P[(2*16 + li)*XSTR + kbase];
            #pragma unroll
            for (int b = 0; b < 4; ++b) {
                bf16x8 XB = *(const bf16x8*)&XT[(b*16 + li)*XSTR + kbase];
                acc2[0][b] = __builtin_amdgcn_mfma_f32_16x16x32_bf16(PA0, XB, acc2[0][b], 0, 0, 0);
                acc2[1][b] = __builtin_amdgcn_mfma_f32_16x16x32_bf16(PA1, XB, acc2[1][b], 0, 0, 0);
                acc2[2][b] = __builtin_amdgcn_mfma_f32_16x16x32_bf16(PA2, XB, acc2[2][b], 0, 0, 0);
            }
            acc2[0][4] = __builtin_amdgcn_mfma_f32_16x16x32_bf16(PA0, XB4, acc2[0][4], 0, 0, 0);
            acc2[1][4] = __builtin_amdgcn_mfma_f32_16x16x32_bf16(PA1, XB4, acc2[1][4], 0, 0, 0);
            acc2[2][4] = __builtin_amdgcn_mfma_f32_16x16x32_bf16(PA2, XB4, acc2[2][4], 0, 0, 0);
        }
    }

    // ---- block-level reduce of acc2 across waves, then PLAIN stores to this block's slot ----
    __syncthreads();
    for (int i = tid; i < 48*84; i += 256) ACCR[i] = 0.0f;
    __syncthreads();
    #pragma unroll
    for (int a = 0; a < 3; ++a)
        #pragma unroll
        for (int b = 0; b < 5; ++b)
            #pragma unroll
            for (int r = 0; r < 4; ++r)
                atomicAdd(&ACCR[(a*16 + lg*4 + r)*84 + b*16 + li], acc2[a][b][r]);
    __syncthreads();
    {
        float* ppart = outp + (size_t)(side*BPS3 + bloc) * 2600;   // disjoint slot in d_out
        for (int i = tid; i < 2600; i += 256) {
            const int hc = i / 65, j = i - hc*65;
            ppart[i] = ACCR[hc*84 + j];
        }
    }
}

// ---------------- kernel R: reduce BPS3 partial slots (in d_out) -> gacc totals (in ws) ----------------
__global__ __launch_bounds__(256) void kR(const float* __restrict__ outp, float* __restrict__ ws)
{
    const int gid = blockIdx.x * 256 + threadIdx.x;
    if (gid >= 2*2600) return;
    const int side = gid / 2600, i = gid - side*2600;
    const float* part = outp + (size_t)side * BPS3 * 2600;
    float s = 0.0f;
    #pragma unroll 8
    for (int k = 0; k < BPS3; ++k) s += part[(size_t)k*2600 + i];
    float* gacc = ws + (side ? OFF_ACC_C : OFF_ACC_V);
    gacc[acc_dst(i)] = s;
}

// ---------------- kernel C: class-level finalize -> fused[c][e] ----------------
__global__ __launch_bounds__(512) void kC(
    const float* __restrict__ sem_v, const float* __restrict__ sem_c,
    const float* __restrict__ Wqkv_v, const float* __restrict__ bqkv_v,
    const float* __restrict__ Wqkv_c, const float* __restrict__ bqkv_c,
    const float* __restrict__ Wo_v, const float* __restrict__ bo_v,
    const float* __restrict__ Wo_c, const float* __restrict__ bo_c,
    const float* __restrict__ Wr_v, const float* __restrict__ br_v,
    const float* __restrict__ Wr_c, const float* __restrict__ br_c,
    const float* __restrict__ Wg_v, const float* __restrict__ bg_v,
    const float* __restrict__ Wg_c, const float* __restrict__ bg_c,
    const float* __restrict__ gamma, const float* __restrict__ beta,
    float* __restrict__ ws)
{
    const int side = blockIdx.x;
    const float* sem  = side ? sem_c  : sem_v;
    const float* Wqkv = side ? Wqkv_c : Wqkv_v;
    const float* bqkv = side ? bqkv_c : bqkv_v;
    const float* Wo = side ? Wo_c : Wo_v;  const float* bo = side ? bo_c : bo_v;
    const float* Wr = side ? Wr_c : Wr_v;  const float* br = side ? br_c : br_v;
    const float* Wg = side ? Wg_c : Wg_v;  const float* bg = side ? bg_c : bg_v;
    const float* gacc = ws + (side ? OFF_ACC_C : OFF_ACC_V);
    float* fused = ws + (side ? OFF_FUSED_C : OFF_FUSED_V);
    const float* Wv = Wqkv + 2*E*E;
    const float* bv = bqkv + 2*E;

    const int tid = threadIdx.x;
    const int c = tid >> 6, e = tid & 63, h = e >> 4;

    __shared__ float s_a[NC][E];
    __shared__ float s_b[NC][E];
    __shared__ float s_old[NC][E];
    __shared__ float s_new[NC][E];

    const float Z = gacc[ACC_P + h*8 + c];
    float s = 0.0f;
    for (int j = 0; j < 64; ++j) s += gacc[ACC_SXW + (h*64 + j)*8 + c] * Wv[e*64 + j];
    s_a[c][e] = bv[e] + s / Z;
    __syncthreads();

    float s2 = bo[e];
    for (int j = 0; j < 64; ++j) s2 += s_a[c][j] * Wo[e*64 + j];
    s_b[c][e] = s2;
    const float cnt = gacc[ACC_CNT + c];
    const float oldv = gacc[ACC_AXS + e*8 + c] / fmaxf(cnt, 1.0f);
    s_old[c][e] = oldv;
    __syncthreads();

    float s3 = br[e];
    for (int j = 0; j < 64; ++j) s3 += sem[c*64 + j] * Wr[e*128 + j];
    for (int j = 0; j < 64; ++j) s3 += s_b[c][j]    * Wr[e*128 + 64 + j];
    s_new[c][e] = s3;
    __syncthreads();

    float s4 = bg[e];
    for (int j = 0; j < 64; ++j) s4 += s_old[c][j] * Wg[e*128 + j];
    for (int j = 0; j < 64; ++j) s4 += s_new[c][j] * Wg[e*128 + 64 + j];
    const float g = 1.0f / (1.0f + __expf(-s4));
    const float f = g * oldv + (1.0f - g) * s3;

    float sum = f;
    for (int m = 32; m >= 1; m >>= 1) sum += __shfl_xor(sum, m, 64);
    const float mu = sum * (1.0f/64.0f);
    const float d  = f - mu;
    float sq = d * d;
    for (int m = 32; m >= 1; m >>= 1) sq += __shfl_xor(sq, m, 64);
    const float var = sq * (1.0f/64.0f);
    fused[c*64 + e] = d * rsqrtf(var + 1e-5f) * gamma[e] + beta[e];
}

// ---------------- kernel D: out[n] = fused[cls[n]] * x[n]  (fully overwrites d_out) ----------------
__global__ __launch_bounds__(256) void kD(
    const float* __restrict__ xv, const float* __restrict__ xc,
    const int* __restrict__ clsv, const int* __restrict__ clsc,
    const float* __restrict__ ws, float* __restrict__ out)
{
    const int stride = gridDim.x * blockDim.x;
    const int TOT = 2 * N_NODES * 16;
    for (int i = blockIdx.x * blockDim.x + threadIdx.x; i < TOT; i += stride) {
        const int side  = i >= N_NODES * 16;
        const int local = side ? i - N_NODES * 16 : i;
        const int n = local >> 4;
        const int cc = side ? clsc[n] : clsv[n];
        const float* fu = ws + (side ? OFF_FUSED_C : OFF_FUSED_V);
        const float4 f  = reinterpret_cast<const float4*>(fu)[cc*16 + (local & 15)];
        const float* x  = side ? xc : xv;
        const float4 x4 = reinterpret_cast<const float4*>(x)[local];
        float4 o;
        o.x = f.x * x4.x; o.y = f.y * x4.y; o.z = f.z * x4.z; o.w = f.w * x4.w;
        reinterpret_cast<float4*>(out)[i] = o;
    }
}

extern "C" void kernel_launch(void* const* d_in, const int* in_sizes, int n_in,
                              void* d_out, int out_size, void* d_ws, size_t ws_size,
                              hipStream_t stream) {
    const float* v      = (const float*)d_in[0];
    const float* c      = (const float*)d_in[1];
    const float* v_sem  = (const float*)d_in[2];
    const float* c_sem  = (const float*)d_in[3];
    const int*   v_cls  = (const int*)d_in[4];
    const int*   c_cls  = (const int*)d_in[5];
    const float* Ws_v   = (const float*)d_in[6],  *bs_v   = (const float*)d_in[7];
    const float* Ws_c   = (const float*)d_in[8],  *bs_c   = (const float*)d_in[9];
    const float* Wqkv_v = (const float*)d_in[10], *bqkv_v = (const float*)d_in[11];
    const float* Wo_v   = (const float*)d_in[12], *bo_v   = (const float*)d_in[13];
    const float* Wqkv_c = (const float*)d_in[14], *bqkv_c = (const float*)d_in[15];
    const float* Wo_c   = (const float*)d_in[16], *bo_c   = (const float*)d_in[17];
    const float* Wr_v   = (const float*)d_in[18], *br_v   = (const float*)d_in[19];
    const float* Wr_c   = (const float*)d_in[20], *br_c   = (const float*)d_in[21];
    const float* Wg_v   = (const float*)d_in[22], *bg_v   = (const float*)d_in[23];
    const float* Wg_c   = (const float*)d_in[24], *bg_c   = (const float*)d_in[25];
    const float* gamma  = (const float*)d_in[26], *beta   = (const float*)d_in[27];
    float* ws  = (float*)d_ws;
    float* out = (float*)d_out;

    kQ<<<2, 512, 0, stream>>>(v_sem, c_sem, Wqkv_v, bqkv_v, Wqkv_c, bqkv_c,
                              Ws_v, bs_v, Ws_c, bs_c, ws);
    kA<<<2*BPS3, 256, 0, stream>>>(v, c, v_cls, c_cls, Ws_v, bs_v, Ws_c, bs_c, ws, out);
    kR<<<21, 256, 0, stream>>>(out, ws);
    kC<<<2, 512, 0, stream>>>(v_sem, c_sem, Wqkv_v, bqkv_v, Wqkv_c, bqkv_c,
                              Wo_v, bo_v, Wo_c, bo_c, Wr_v, br_v, Wr_c, br_c,
                              Wg_v, bg_v, Wg_c, bg_c, gamma, beta, ws);
    kD<<<4096, 256, 0, stream>>>(v, c, v_cls, c_cls, ws, out);
}

// Round 16
// 253.891 us; speedup vs baseline: 2.0095x; 2.0095x over previous
//
#include <hip/hip_runtime.h>
#include <math.h>

#define N_NODES 524288
#define E 64
#define NC 8
#define TILE 128
#define BPS3 256                 // kA blocks per side
#define ITERS3 16                // 256 blocks * 16 tiles * 128 nodes = 524288

// ---- workspace layout (float offsets) ----
#define OFF_WQ_V    0      // WQ[hc][j]  hc=h*8+c  (2048)
#define OFF_SB_V    2048   // sbias[hc]            (32)
#define OFF_WQ_C    2080
#define OFF_SB_C    4128
#define OFF_ACC_V   4160   // 2600 floats (totals, written by kR)
#define OFF_ACC_C   6760
#define OFF_FUSED_V 9360   // 512
#define OFF_FUSED_C 9872
// gacc internal layout:
#define ACC_SXW 0      // [(h*64+j)*8 + c]  (2048)  sum of p_h * xs_j per class
#define ACC_AXS 2048   // [j*8 + c]         (512)   sum of xs_j per class
#define ACC_P   2560   // [h*8 + c]         (32)    sum of p_h per class
#define ACC_CNT 2592   // [c]               (8)
#define ACC_TOTAL 2600

#define XSTR 136       // halfword stride for XT / P rows (272B, 16B-aligned)

typedef __attribute__((ext_vector_type(8))) short bf16x8;
typedef __attribute__((ext_vector_type(4))) float f32x4;

__device__ __forceinline__ unsigned short f2bf(float f) {
    union { float f; unsigned u; } v; v.f = f;
    return (unsigned short)((v.u + 0x7fffu + ((v.u >> 16) & 1u)) >> 16);  // RNE
}
__device__ __forceinline__ float bf2f(unsigned short s) {
    union { unsigned u; float f; } v; v.u = ((unsigned)s) << 16;
    return v.f;
}
__device__ __forceinline__ bf16x8 pack8s(float4 a, float4 b) {
    bf16x8 r;
    r[0] = (short)f2bf(a.x); r[1] = (short)f2bf(a.y);
    r[2] = (short)f2bf(a.z); r[3] = (short)f2bf(a.w);
    r[4] = (short)f2bf(b.x); r[5] = (short)f2bf(b.y);
    r[6] = (short)f2bf(b.z); r[7] = (short)f2bf(b.w);
    return r;
}
__device__ __forceinline__ bf16x8 load8bf(const float* p) {
    return pack8s(*(const float4*)p, *(const float4*)(p + 4));
}

// map flat partial index i (= hc*65+j, hc<40) to gacc offset
__device__ __forceinline__ int acc_dst(int i) {
    const int hc = i / 65, j = i - hc*65;
    if (hc < 32) return (j < 64) ? (ACC_SXW + ((hc>>3)*64 + j)*8 + (hc&7)) : (ACC_P + hc);
    const int c2 = hc - 32;
    return (j < 64) ? (ACC_AXS + j*8 + c2) : (ACC_CNT + c2);
}

// ---------------- kernel Q: fold Wq,Wk,Ws into WQ/sbias ----------------
__global__ __launch_bounds__(512) void kQ(
    const float* __restrict__ sem_v, const float* __restrict__ sem_c,
    const float* __restrict__ Wqkv_v, const float* __restrict__ bqkv_v,
    const float* __restrict__ Wqkv_c, const float* __restrict__ bqkv_c,
    const float* __restrict__ Ws_v, const float* __restrict__ bs_v,
    const float* __restrict__ Ws_c, const float* __restrict__ bs_c,
    float* __restrict__ ws)
{
    const int side = blockIdx.x;
    const float* sem  = side ? sem_c  : sem_v;
    const float* Wqkv = side ? Wqkv_c : Wqkv_v;
    const float* bqkv = side ? bqkv_c : bqkv_v;
    const float* Ws   = side ? Ws_c   : Ws_v;
    const float* bs   = side ? bs_c   : bs_v;
    float* WQo  = ws + (side ? OFF_WQ_C : OFF_WQ_V);
    float* sbo  = ws + (side ? OFF_SB_C : OFF_SB_V);
    const int tid = threadIdx.x;

    __shared__ float s_q[NC][E];
    __shared__ float s_qk[32][E];   // [hc][e]
    {   // q[c][e] = (bq[e] + sem[c]·Wq[e]) * (1/sqrt(16))
        const int c = tid >> 6, e = tid & 63;
        float a = bqkv[e];
        for (int j = 0; j < E; ++j) a += sem[c*E + j] * Wqkv[e*E + j];
        s_q[c][e] = a * 0.25f;
    }
    __syncthreads();

    const float* Wk = Wqkv + E*E;
    const float* bk = bqkv + E;
    for (int r = 0; r < 4; ++r) {
        int idx = r*512 + tid;             // idx = hc*64 + e
        int hc = idx >> 6, e = idx & 63;
        int h = hc >> 3, c = hc & 7;
        float a = 0.0f;
        for (int d = 0; d < 16; ++d) a += Wk[(h*16+d)*E + e] * s_q[c][h*16+d];
        s_qk[hc][e] = a;
    }
    __syncthreads();

    // WQ[hc][j] = sum_e qk[hc][e] * Ws[e][j]
    for (int r = 0; r < 4; ++r) {
        int idx = r*512 + tid;
        int hc = idx >> 6, j = idx & 63;
        float a = 0.0f;
        for (int e = 0; e < 64; ++e) a += s_qk[hc][e] * Ws[e*64 + j];
        WQo[idx] = a;
    }
    // sbias[hc] = qb[hc] + sum_e qk[hc][e]*bs[e]
    if (tid < 32) {
        int hc = tid, h = hc >> 3, c = hc & 7;
        float a = 0.0f;
        for (int d = 0; d < 16; ++d) a += bk[h*16+d] * s_q[c][h*16+d];
        for (int e = 0; e < 64; ++e) a += s_qk[hc][e] * bs[e];
        sbo[tid] = a;
    }
}

// ---------------- kernel A: double-MFMA segment attention, barrier-free hot loop ----------------
// R13 exactly (session best: kA 154 us, total 254 us). Register model from
// R8/R10/R15: this body needs ~180 unified regs -> 2 wave-slots is the no-spill
// optimum; bounds=3/4 spill (FETCH 630-900 MB), diet bodies lose the prefetch.
// Flush = plain stores to disjoint d_out slots (no atomics; the R13 win:
// WRITE_SIZE 41.6 MB -> 5.2 MB, kA 235 -> 154 us).
__global__ __launch_bounds__(256, 2) void kA(
    const float* __restrict__ xv, const float* __restrict__ xc,
    const int* __restrict__ clsv, const int* __restrict__ clsc,
    const float* __restrict__ Ws_v, const float* __restrict__ bs_v,
    const float* __restrict__ Ws_c, const float* __restrict__ bs_c,
    float* __restrict__ ws, float* __restrict__ outp)
{
    const int bid  = blockIdx.x;
    const int side = bid >> 8;
    const float* x    = side ? xc   : xv;
    const int*   cls  = side ? clsc : clsv;
    const float* Ws   = side ? Ws_c : Ws_v;
    const float* bs   = side ? bs_c : bs_v;
    const float* WQ   = ws + (side ? OFF_WQ_C : OFF_WQ_V);
    const float* sbia = ws + (side ? OFF_SB_C : OFF_SB_V);
    const int tid  = threadIdx.x;
    const int w    = tid >> 6;
    const int lane = tid & 63;
    const int li   = lane & 15, lg = lane >> 4;

    // LDS: XT 64x136 bf16 (17408 B) | P 48x136 bf16 (13056 B) | SC 128x33 f32 (16896 B) = 47360 B
    // ACCR (48x84 f32 = 16128 B) aliases XT; only touched after the post-loop __syncthreads().
    __shared__ __align__(16) unsigned char smem[47360];
    unsigned short* XT = (unsigned short*)(smem);
    unsigned short* P  = (unsigned short*)(smem + 17408);
    float*          SC = (float*)(smem + 30464);
    float*        ACCR = (float*)(smem);

    // ---- A-fragments: rows 0..63 = Ws (e), rows 64..95 = WQ (hc). Held in regs all kernel.
    bf16x8 AF[6][2];
    #pragma unroll
    for (int mb = 0; mb < 6; ++mb) {
        const int m = mb*16 + li;
        const float* src = (mb < 4) ? (Ws + m*64) : (WQ + (m - 64)*64);
        #pragma unroll
        for (int kb = 0; kb < 2; ++kb)
            AF[mb][kb] = load8bf(src + kb*32 + lg*8);
    }
    // per-thread bias registers (row-indexed: C/D row = lg*4+r)
    float bsr[16], sbr[8];
    #pragma unroll
    for (int mb = 0; mb < 4; ++mb)
        #pragma unroll
        for (int r = 0; r < 4; ++r) bsr[mb*4+r] = bs[mb*16 + lg*4 + r];
    #pragma unroll
    for (int sb = 0; sb < 2; ++sb)
        #pragma unroll
        for (int r = 0; r < 4; ++r) sbr[sb*4+r] = sbia[sb*16 + lg*4 + r];

    // constant "ones" B-block for MFMA2 (e-cols 64..79: col 64 = 1, rest 0)
    bf16x8 XB4;
    {
        const short v = (li == 0) ? (short)0x3F80 : (short)0;
        #pragma unroll
        for (int j = 0; j < 8; ++j) XB4[j] = v;
    }

    // P padding rows 40..47: zero once, read-only afterwards (barrier outside loop)
    for (int i = tid; i < 8*XSTR; i += 256) P[40*XSTR + i] = 0;
    __syncthreads();

    f32x4 acc2[3][5];
    #pragma unroll
    for (int a = 0; a < 3; ++a)
        #pragma unroll
        for (int b = 0; b < 5; ++b) acc2[a][b] = (f32x4){0.f,0.f,0.f,0.f};

    const int bloc = bid & (BPS3 - 1);

    // ---- depth-1 register prefetch of the x-tile + class (wave-own node) ----
    float4 pf[8];
    int pcls;
    {
        const int tb = (bloc * ITERS3) * TILE;
        #pragma unroll
        for (int nb = 0; nb < 2; ++nb) {
            const int nt = w*32 + nb*16 + li;
            const float* xp = x + (size_t)(tb + nt)*64 + lg*8;
            pf[nb*4+0] = *(const float4*)xp;
            pf[nb*4+1] = *(const float4*)(xp + 4);
            pf[nb*4+2] = *(const float4*)(xp + 32);
            pf[nb*4+3] = *(const float4*)(xp + 36);
        }
        pcls = cls[tb + w*32 + (lane & 31)];
    }

    for (int t = 0; t < ITERS3; ++t) {
        // consume prefetched tile into bf16 fragments
        bf16x8 B00 = pack8s(pf[0], pf[1]);
        bf16x8 B01 = pack8s(pf[2], pf[3]);
        bf16x8 B10 = pack8s(pf[4], pf[5]);
        bf16x8 B11 = pack8s(pf[6], pf[7]);
        const int myc = pcls;

        // issue next tile's loads now (consumed next iteration)
        if (t + 1 < ITERS3) {
            const int tb = (bloc * ITERS3 + t + 1) * TILE;
            #pragma unroll
            for (int nb = 0; nb < 2; ++nb) {
                const int nt = w*32 + nb*16 + li;
                const float* xp = x + (size_t)(tb + nt)*64 + lg*8;
                pf[nb*4+0] = *(const float4*)xp;
                pf[nb*4+1] = *(const float4*)(xp + 4);
                pf[nb*4+2] = *(const float4*)(xp + 32);
                pf[nb*4+3] = *(const float4*)(xp + 36);
            }
            pcls = cls[tb + w*32 + (lane & 31)];
        }

        // ---- MFMA1: [Ws;WQ] @ x^T -> xs^T (to XT, bf16) and scores (to SC, f32) ----
        #pragma unroll
        for (int nb = 0; nb < 2; ++nb) {
            const int nt = w*32 + nb*16 + li;
            const bf16x8 Bk0 = nb ? B10 : B00;
            const bf16x8 Bk1 = nb ? B11 : B01;
            f32x4 Cf[6];
            #pragma unroll
            for (int mb = 0; mb < 6; ++mb) {
                f32x4 c0 = {0.f, 0.f, 0.f, 0.f};
                c0 = __builtin_amdgcn_mfma_f32_16x16x32_bf16(AF[mb][0], Bk0, c0, 0, 0, 0);
                c0 = __builtin_amdgcn_mfma_f32_16x16x32_bf16(AF[mb][1], Bk1, c0, 0, 0, 0);
                Cf[mb] = c0;
            }
            // xs^T rows: e = mb*16 + lg*4 + r, col = nt
            #pragma unroll
            for (int mb = 0; mb < 4; ++mb)
                #pragma unroll
                for (int r = 0; r < 4; ++r)
                    XT[(mb*16 + lg*4 + r)*XSTR + nt] = f2bf(Cf[mb][r] + bsr[mb*4+r]);
            // scores: hc = sb*16 + lg*4 + r
            #pragma unroll
            for (int sb = 0; sb < 2; ++sb)
                #pragma unroll
                for (int r = 0; r < 4; ++r)
                    SC[nt*33 + sb*16 + lg*4 + r] = Cf[4+sb][r] + sbr[sb*4+r];
        }
        // zero this wave's P column strip (rows 0..39)
        {
            const uint4 z4 = {0u,0u,0u,0u};
            for (int i = lane; i < 160; i += 64) {
                const int row = i >> 2, cg = i & 3;
                *(uint4*)&P[row*XSTR + w*32 + cg*8] = z4;
            }
        }

        // ---- p = exp(score): lane handles node w*32+(lane&31), heads 2*(lane>>5)..+1 ----
        // (wave-private: reads SC / writes P only in this wave's column strip)
        {
            const int nt = w*32 + (lane & 31), hp = lane >> 5;
            const float sa  = SC[nt*33 + (hp*2    )*8 + myc];
            const float sb2 = SC[nt*33 + (hp*2 + 1)*8 + myc];
            // softmax-max skipped: |scores| << 1 at this weight scale (shift-invariant w)
            P[((hp*2    )*8 + myc)*XSTR + nt] = f2bf(__expf(sa));
            P[((hp*2 + 1)*8 + myc)*XSTR + nt] = f2bf(__expf(sb2));
            if (hp == 0) P[(32 + myc)*XSTR + nt] = 0x3F80;   // indicator row
        }

        // ---- MFMA2: ACC[48 hc][80 e] += P @ [xs | 1]; wave w covers its own 32-node k-range ----
        {
            const int kbase = w*32 + lg*8;
            bf16x8 PA0 = *(const bf16x8*)&P[(0*16 + li)*XSTR + kbase];
            bf16x8 PA1 = *(const bf16x8*)&P[(1*16 + li)*XSTR + kbase];
            bf16x8 PA2 = *(const bf16x8*)&P[(2*16 + li)*XSTR + kbase];
            #pragma unroll
            for (int b = 0; b < 4; ++b) {
                bf16x8 XB = *(const bf16x8*)&XT[(b*16 + li)*XSTR + kbase];
                acc2[0][b] = __builtin_amdgcn_mfma_f32_16x16x32_bf16(PA0, XB, acc2[0][b], 0, 0, 0);
                acc2[1][b] = __builtin_amdgcn_mfma_f32_16x16x32_bf16(PA1, XB, acc2[1][b], 0, 0, 0);
                acc2[2][b] = __builtin_amdgcn_mfma_f32_16x16x32_bf16(PA2, XB, acc2[2][b], 0, 0, 0);
            }
            acc2[0][4] = __builtin_amdgcn_mfma_f32_16x16x32_bf16(PA0, XB4, acc2[0][4], 0, 0, 0);
            acc2[1][4] = __builtin_amdgcn_mfma_f32_16x16x32_bf16(PA1, XB4, acc2[1][4], 0, 0, 0);
            acc2[2][4] = __builtin_amdgcn_mfma_f32_16x16x32_bf16(PA2, XB4, acc2[2][4], 0, 0, 0);
        }
    }

    // ---- block-level reduce of acc2 across waves, then PLAIN stores to this block's slot ----
    __syncthreads();
    for (int i = tid; i < 48*84; i += 256) ACCR[i] = 0.0f;
    __syncthreads();
    #pragma unroll
    for (int a = 0; a < 3; ++a)
        #pragma unroll
        for (int b = 0; b < 5; ++b)
            #pragma unroll
            for (int r = 0; r < 4; ++r)
                atomicAdd(&ACCR[(a*16 + lg*4 + r)*84 + b*16 + li], acc2[a][b][r]);
    __syncthreads();
    {
        float* ppart = outp + (size_t)(side*BPS3 + bloc) * 2600;   // disjoint slot in d_out
        for (int i = tid; i < 2600; i += 256) {
            const int hc = i / 65, j = i - hc*65;
            ppart[i] = ACCR[hc*84 + j];
        }
    }
}

// ---------------- kernel R: reduce BPS3 partial slots (in d_out) -> gacc totals (in ws) ----------------
__global__ __launch_bounds__(256) void kR(const float* __restrict__ outp, float* __restrict__ ws)
{
    const int gid = blockIdx.x * 256 + threadIdx.x;
    if (gid >= 2*2600) return;
    const int side = gid / 2600, i = gid - side*2600;
    const float* part = outp + (size_t)side * BPS3 * 2600;
    float s = 0.0f;
    #pragma unroll 8
    for (int k = 0; k < BPS3; ++k) s += part[(size_t)k*2600 + i];
    float* gacc = ws + (side ? OFF_ACC_C : OFF_ACC_V);
    gacc[acc_dst(i)] = s;
}

// ---------------- kernel C: class-level finalize -> fused[c][e] ----------------
__global__ __launch_bounds__(512) void kC(
    const float* __restrict__ sem_v, const float* __restrict__ sem_c,
    const float* __restrict__ Wqkv_v, const float* __restrict__ bqkv_v,
    const float* __restrict__ Wqkv_c, const float* __restrict__ bqkv_c,
    const float* __restrict__ Wo_v, const float* __restrict__ bo_v,
    const float* __restrict__ Wo_c, const float* __restrict__ bo_c,
    const float* __restrict__ Wr_v, const float* __restrict__ br_v,
    const float* __restrict__ Wr_c, const float* __restrict__ br_c,
    const float* __restrict__ Wg_v, const float* __restrict__ bg_v,
    const float* __restrict__ Wg_c, const float* __restrict__ bg_c,
    const float* __restrict__ gamma, const float* __restrict__ beta,
    float* __restrict__ ws)
{
    const int side = blockIdx.x;
    const float* sem  = side ? sem_c  : sem_v;
    const float* Wqkv = side ? Wqkv_c : Wqkv_v;
    const float* bqkv = side ? bqkv_c : bqkv_v;
    const float* Wo = side ? Wo_c : Wo_v;  const float* bo = side ? bo_c : bo_v;
    const float* Wr = side ? Wr_c : Wr_v;  const float* br = side ? br_c : br_v;
    const float* Wg = side ? Wg_c : Wg_v;  const float* bg = side ? bg_c : bg_v;
    const float* gacc = ws + (side ? OFF_ACC_C : OFF_ACC_V);
    float* fused = ws + (side ? OFF_FUSED_C : OFF_FUSED_V);
    const float* Wv = Wqkv + 2*E*E;
    const float* bv = bqkv + 2*E;

    const int tid = threadIdx.x;
    const int c = tid >> 6, e = tid & 63, h = e >> 4;

    __shared__ float s_a[NC][E];
    __shared__ float s_b[NC][E];
    __shared__ float s_old[NC][E];
    __shared__ float s_new[NC][E];

    const float Z = gacc[ACC_P + h*8 + c];
    float s = 0.0f;
    for (int j = 0; j < 64; ++j) s += gacc[ACC_SXW + (h*64 + j)*8 + c] * Wv[e*64 + j];
    s_a[c][e] = bv[e] + s / Z;
    __syncthreads();

    float s2 = bo[e];
    for (int j = 0; j < 64; ++j) s2 += s_a[c][j] * Wo[e*64 + j];
    s_b[c][e] = s2;
    const float cnt = gacc[ACC_CNT + c];
    const float oldv = gacc[ACC_AXS + e*8 + c] / fmaxf(cnt, 1.0f);
    s_old[c][e] = oldv;
    __syncthreads();

    float s3 = br[e];
    for (int j = 0; j < 64; ++j) s3 += sem[c*64 + j] * Wr[e*128 + j];
    for (int j = 0; j < 64; ++j) s3 += s_b[c][j]    * Wr[e*128 + 64 + j];
    s_new[c][e] = s3;
    __syncthreads();

    float s4 = bg[e];
    for (int j = 0; j < 64; ++j) s4 += s_old[c][j] * Wg[e*128 + j];
    for (int j = 0; j < 64; ++j) s4 += s_new[c][j] * Wg[e*128 + 64 + j];
    const float g = 1.0f / (1.0f + __expf(-s4));
    const float f = g * oldv + (1.0f - g) * s3;

    float sum = f;
    for (int m = 32; m >= 1; m >>= 1) sum += __shfl_xor(sum, m, 64);
    const float mu = sum * (1.0f/64.0f);
    const float d  = f - mu;
    float sq = d * d;
    for (int m = 32; m >= 1; m >>= 1) sq += __shfl_xor(sq, m, 64);
    const float var = sq * (1.0f/64.0f);
    fused[c*64 + e] = d * rsqrtf(var + 1e-5f) * gamma[e] + beta[e];
}

// ---------------- kernel D: out[n] = fused[cls[n]] * x[n]  (fully overwrites d_out) ----------------
__global__ __launch_bounds__(256) void kD(
    const float* __restrict__ xv, const float* __restrict__ xc,
    const int* __restrict__ clsv, const int* __restrict__ clsc,
    const float* __restrict__ ws, float* __restrict__ out)
{
    const int stride = gridDim.x * blockDim.x;
    const int TOT = 2 * N_NODES * 16;
    for (int i = blockIdx.x * blockDim.x + threadIdx.x; i < TOT; i += stride) {
        const int side  = i >= N_NODES * 16;
        const int local = side ? i - N_NODES * 16 : i;
        const int n = local >> 4;
        const int cc = side ? clsc[n] : clsv[n];
        const float* fu = ws + (side ? OFF_FUSED_C : OFF_FUSED_V);
        const float4 f  = reinterpret_cast<const float4*>(fu)[cc*16 + (local & 15)];
        const float* x  = side ? xc : xv;
        const float4 x4 = reinterpret_cast<const float4*>(x)[local];
        float4 o;
        o.x = f.x * x4.x; o.y = f.y * x4.y; o.z = f.z * x4.z; o.w = f.w * x4.w;
        reinterpret_cast<float4*>(out)[i] = o;
    }
}

extern "C" void kernel_launch(void* const* d_in, const int* in_sizes, int n_in,
                              void* d_out, int out_size, void* d_ws, size_t ws_size,
                              hipStream_t stream) {
    const float* v      = (const float*)d_in[0];
    const float* c      = (const float*)d_in[1];
    const float* v_sem  = (const float*)d_in[2];
    const float* c_sem  = (const float*)d_in[3];
    const int*   v_cls  = (const int*)d_in[4];
    const int*   c_cls  = (const int*)d_in[5];
    const float* Ws_v   = (const float*)d_in[6],  *bs_v   = (const float*)d_in[7];
    const float* Ws_c   = (const float*)d_in[8],  *bs_c   = (const float*)d_in[9];
    const float* Wqkv_v = (const float*)d_in[10], *bqkv_v = (const float*)d_in[11];
    const float* Wo_v   = (const float*)d_in[12], *bo_v   = (const float*)d_in[13];
    const float* Wqkv_c = (const float*)d_in[14], *bqkv_c = (const float*)d_in[15];
    const float* Wo_c   = (const float*)d_in[16], *bo_c   = (const float*)d_in[17];
    const float* Wr_v   = (const float*)d_in[18], *br_v   = (const float*)d_in[19];
    const float* Wr_c   = (const float*)d_in[20], *br_c   = (const float*)d_in[21];
    const float* Wg_v   = (const float*)d_in[22], *bg_v   = (const float*)d_in[23];
    const float* Wg_c   = (const float*)d_in[24], *bg_c   = (const float*)d_in[25];
    const float* gamma  = (const float*)d_in[26], *beta   = (const float*)d_in[27];
    float* ws  = (float*)d_ws;
    float* out = (float*)d_out;

    kQ<<<2, 512, 0, stream>>>(v_sem, c_sem, Wqkv_v, bqkv_v, Wqkv_c, bqkv_c,
                              Ws_v, bs_v, Ws_c, bs_c, ws);
    kA<<<2*BPS3, 256, 0, stream>>>(v, c, v_cls, c_cls, Ws_v, bs_v, Ws_c, bs_c, ws, out);
    kR<<<21, 256, 0, stream>>>(out, ws);
    kC<<<2, 512, 0, stream>>>(v_sem, c_sem, Wqkv_v, bqkv_v, Wqkv_c, bqkv_c,
                              Wo_v, bo_v, Wo_c, bo_c, Wr_v, br_v, Wr_c, br_c,
                              Wg_v, bg_v, Wg_c, bg_c, gamma, beta, ws);
    kD<<<4096, 256, 0, stream>>>(v, c, v_cls, c_cls, ws, out);
}